// Round 11
// baseline (112.874 us; speedup 1.0000x reference)
//
#include <hip/hip_runtime.h>

#define EMB_DIM 256
#define HW 4096
#define N_EMB 1024
#define TOT_ELEMS (32 * HW * EMB_DIM)   // 33554432

typedef __attribute__((ext_vector_type(4))) float f32x4;
typedef unsigned long long u64;

// ws layout (bytes)
#define WS_EMBQ_OFF 0             // 256 KB fp8(e4m3) swizzled emb, 16 chunks x 16KB
#define WS_E2_OFF   262144        // 1024 f32 ||e||^2 (fp32-exact)
#define WS_PSC_OFF  266240        // 512 f32 block partials

#define MAIN_BLOCKS 512           // 256 rows/block: 4 waves x (32 SB0 + 32 SB1)
#define ESCALE 65536.0f           // emb pre-scale: |e|<2^-10 -> |ê|<64 (normal e4m3)
#define INV2SCALE 3.0517578125e-5f // 2/65536, exact fp32

typedef const __attribute__((address_space(1))) unsigned int* gas_u32p;
typedef __attribute__((address_space(3))) unsigned int* las_u32p;
__device__ __forceinline__ void gll16(const void* g, void* l) {
    __builtin_amdgcn_global_load_lds((gas_u32p)g, (las_u32p)l, 16, 0, 0);
}

// ---------------------------------------------------------------------------
// Kernel 0: emb fp32 -> fp8 e4m3 (x65536), swizzled chunk layout + e2=||e||^2.
// (verified R8/R10: correct fp8 numerics, 0 LDS bank conflicts on the reader)
// ---------------------------------------------------------------------------
__global__ __launch_bounds__(64) void prep_emb(const float* __restrict__ emb,
                                               char* __restrict__ embq,
                                               float* __restrict__ e2) {
    const int e = blockIdx.x, ln = threadIdx.x;
    const float4 v = reinterpret_cast<const float4*>(emb)[e * 64 + ln];
    float s = v.x * v.x + v.y * v.y + v.z * v.z + v.w * v.w;

    unsigned d = 0;
    d = (unsigned)__builtin_amdgcn_cvt_pk_fp8_f32(v.x * ESCALE, v.y * ESCALE, (int)d, false);
    d = (unsigned)__builtin_amdgcn_cvt_pk_fp8_f32(v.z * ESCALE, v.w * ESCALE, (int)d, true);

    const int el = e & 63, ch = e >> 6;
    const int cb = (ln * 4) ^ ((el & 15) << 3);
    *reinterpret_cast<unsigned*>(embq + ch * 16384 + el * 256 + cb) = d;

#pragma unroll
    for (int o = 32; o; o >>= 1) s += __shfl_down(s, o);
    if (ln == 0) e2[e] = s;
}

// ---------------------------------------------------------------------------
// Kernel 1: fused copy + sum(x^2) + fp8 GEMM + min-reduction.
// PHASE-OVERLAP design (R8's phases summed: ~42us IO + ~34us MFMA serial):
// 512 blocks (2/CU, all resident), 4 waves x 64 rows as 2 sub-batches.
// SB0: R8's verified fenced prologue. SB1: IO pipelined INSIDE SB0's e-loop
// (LOADP at chunk c, STOREP+cvt at c+1 -> loads age ~1240cyc > HBM latency;
// __syncthreads' vmcnt(0) drain is free since all vmem is >=1 chunk old).
// All x-fragments in 64 pinned AGPRs (R4/R6/R8-verified spill fix).
// Loop B re-stages the same 16 chunks for SB1's e-loop.
// MFMA 16x16x32 fp8_fp8: D[e][m]: m=lane&15, e=4*(lane>>4)+reg.
// score = e2 - 2^-15 * (A.B)
// ---------------------------------------------------------------------------
__global__ __launch_bounds__(256)
void vq_main(const float* __restrict__ x,
             float* __restrict__ out,
             const char* __restrict__ embq,
             const float* __restrict__ e2,
             float* __restrict__ psc) {
    __shared__ char smem[32768];           // 2 x 16KB emb chunk buffers
    const int tid = threadIdx.x;
    const int wv = tid >> 6, ln = tid & 63;
    const int u = ln & 15, g = ln >> 4;    // m-lane, k-octet group

    const int row_base = blockIdx.x << 8;  // 256 rows/block
    const int b = row_base >> 12, n_base = row_base & 4095;
    const unsigned base0 = (unsigned)(b * (EMB_DIM * HW) + n_base + wv * 64 + u);
    const unsigned base1 = base0 + 32;     // SB1 rows

#define STAGE(CC, BUF) do {                                                   \
        const char* gs_ = embq + (CC) * 16384 + wv * 4096 + ln * 16;          \
        char* lb_ = smem + (BUF) * 16384 + wv * 4096;                         \
        _Pragma("unroll")                                                     \
        for (int i_ = 0; i_ < 4; ++i_) gll16(gs_ + i_ * 1024, lb_ + i_ * 1024); \
    } while (0)

    // ---- stage emb chunk 0 (overlaps the SB0 prologue) ----
    STAGE(0, 0);

    // ---- SB0 prologue: R8's exact fenced scalar-IO fragment build ----
    float x2s = 0.f;
    long long bx0[8], bx1[8], bx2[8], bx3[8];

#define LDJ(KF, JP, WREG, ZREG, HI) do {                                       \
    const unsigned o_ = base0 + (unsigned)((((KF) * 32 + g * 8 + 2 * (JP))) * HW); \
    const float fa0_ = x[o_],      fb0_ = x[o_ + 16];                          \
    const float fa1_ = x[o_ + HW], fb1_ = x[o_ + HW + 16];                     \
    out[o_] = fa0_;       out[o_ + 16] = fb0_;                                 \
    out[o_ + HW] = fa1_;  out[o_ + HW + 16] = fb1_;                            \
    x2s += fa0_ * fa0_ + fb0_ * fb0_ + fa1_ * fa1_ + fb1_ * fb1_;              \
    WREG = (unsigned)__builtin_amdgcn_cvt_pk_fp8_f32(fa0_, fa1_, (int)WREG, HI); \
    ZREG = (unsigned)__builtin_amdgcn_cvt_pk_fp8_f32(fb0_, fb1_, (int)ZREG, HI); \
} while (0)

#pragma unroll
    for (int kf = 0; kf < 8; ++kf) {
        unsigned w0 = 0, w1 = 0, z0 = 0, z1 = 0;
        LDJ(kf, 0, w0, z0, false);
        LDJ(kf, 1, w0, z0, true);
        LDJ(kf, 2, w1, z1, false);
        LDJ(kf, 3, w1, z1, true);
        bx0[kf] = (long long)(((u64)w1 << 32) | w0);
        bx1[kf] = (long long)(((u64)z1 << 32) | z0);
        asm volatile("" : "+a"(bx0[kf]), "+a"(bx1[kf]));   // pin AGPR
        __builtin_amdgcn_sched_barrier(0);                 // cap loads in flight
    }
#undef LDJ

    // ---- SB1 IO macros: load kf-pair p at chunk p, drain at chunk p+1 ----
    float h[32];
#define LOADP(P) do {                                                          \
        _Pragma("unroll")                                                      \
        for (int jq_ = 0; jq_ < 8; ++jq_) {                                    \
            const int kf_ = 2 * (P) + (jq_ >> 2), jp_ = jq_ & 3;               \
            const unsigned o_ = base1 + (unsigned)((kf_ * 32 + g * 8 + 2 * jp_) * HW); \
            h[4 * jq_ + 0] = x[o_];        h[4 * jq_ + 1] = x[o_ + 16];        \
            h[4 * jq_ + 2] = x[o_ + HW];   h[4 * jq_ + 3] = x[o_ + HW + 16];   \
        }                                                                      \
    } while (0)

#define CVT8(HB, KFI) do {                                                     \
        unsigned w0_ = 0, w1_ = 0, z0_ = 0, z1_ = 0;                           \
        w0_ = (unsigned)__builtin_amdgcn_cvt_pk_fp8_f32(h[HB+0], h[HB+2],  (int)w0_, false); \
        z0_ = (unsigned)__builtin_amdgcn_cvt_pk_fp8_f32(h[HB+1], h[HB+3],  (int)z0_, false); \
        w0_ = (unsigned)__builtin_amdgcn_cvt_pk_fp8_f32(h[HB+4], h[HB+6],  (int)w0_, true);  \
        z0_ = (unsigned)__builtin_amdgcn_cvt_pk_fp8_f32(h[HB+5], h[HB+7],  (int)z0_, true);  \
        w1_ = (unsigned)__builtin_amdgcn_cvt_pk_fp8_f32(h[HB+8], h[HB+10], (int)w1_, false); \
        z1_ = (unsigned)__builtin_amdgcn_cvt_pk_fp8_f32(h[HB+9], h[HB+11], (int)z1_, false); \
        w1_ = (unsigned)__builtin_amdgcn_cvt_pk_fp8_f32(h[HB+12], h[HB+14],(int)w1_, true);  \
        z1_ = (unsigned)__builtin_amdgcn_cvt_pk_fp8_f32(h[HB+13], h[HB+15],(int)z1_, true);  \
        bx2[KFI] = (long long)(((u64)w1_ << 32) | w0_);                        \
        bx3[KFI] = (long long)(((u64)z1_ << 32) | z0_);                        \
        asm volatile("" : "+a"(bx2[KFI]), "+a"(bx3[KFI]));                     \
    } while (0)

#define STOREP(P) do {                                                         \
        _Pragma("unroll")                                                      \
        for (int jq_ = 0; jq_ < 8; ++jq_) {                                    \
            const int kf_ = 2 * (P) + (jq_ >> 2), jp_ = jq_ & 3;               \
            const unsigned o_ = base1 + (unsigned)((kf_ * 32 + g * 8 + 2 * jp_) * HW); \
            out[o_]      = h[4 * jq_ + 0];  out[o_ + 16]      = h[4 * jq_ + 1]; \
            out[o_ + HW] = h[4 * jq_ + 2];  out[o_ + HW + 16] = h[4 * jq_ + 3]; \
            x2s += h[4*jq_+0]*h[4*jq_+0] + h[4*jq_+1]*h[4*jq_+1]               \
                 + h[4*jq_+2]*h[4*jq_+2] + h[4*jq_+3]*h[4*jq_+3];              \
        }                                                                      \
        CVT8(0, 2 * (P));                                                      \
        CVT8(16, 2 * (P) + 1);                                                 \
    } while (0)

#define TLOOP(BXA, BXB, BM0, BM1, CC) do {                                     \
        const char* bufb_ = smem + ((CC) & 1) * 16384;                         \
        _Pragma("unroll")                                                      \
        for (int t_ = 0; t_ < 4; ++t_) {                                       \
            const int rowb_ = (t_ * 16 + u) * 256;                             \
            f32x4 a0_ = {0.f, 0.f, 0.f, 0.f}, a1_ = a0_;                       \
            _Pragma("unroll")                                                  \
            for (int kf_ = 0; kf_ < 8; ++kf_) {                                \
                const int off_ = rowb_ + ((kf_ * 32 + g * 8) ^ swz);           \
                const long long av_ = *reinterpret_cast<const long long*>(bufb_ + off_); \
                a0_ = __builtin_amdgcn_mfma_f32_16x16x32_fp8_fp8(av_, BXA[kf_], a0_, 0, 0, 0); \
                a1_ = __builtin_amdgcn_mfma_f32_16x16x32_fp8_fp8(av_, BXB[kf_], a1_, 0, 0, 0); \
            }                                                                  \
            const f32x4 ev_ = *reinterpret_cast<const f32x4*>(e2 + (CC) * 64 + t_ * 16 + g * 4); \
            _Pragma("unroll")                                                  \
            for (int r_ = 0; r_ < 4; ++r_) {                                   \
                BM0 = fminf(BM0, fmaf(-INV2SCALE, a0_[r_], ev_[r_]));          \
                BM1 = fminf(BM1, fmaf(-INV2SCALE, a1_[r_], ev_[r_]));          \
            }                                                                  \
        }                                                                      \
    } while (0)

    __syncthreads();   // chunk 0 staged (barrier drains vmcnt)

    float b0 = 3.0e38f, b1 = 3.0e38f, b2 = 3.0e38f, b3 = 3.0e38f;
    const int swz = u << 3;

    // ---- loop A: SB0 e-loop with SB1 IO pipelined into chunks 0..4 ----
#pragma unroll
    for (int c = 0; c < 5; ++c) {
        STAGE((c + 1) & 15, (c + 1) & 1);
        __builtin_amdgcn_sched_barrier(0);   // glls issue first
        if (c >= 1) STOREP(c - 1);           // drain pair c-1 (stores + cvt)
        if (c <= 3) LOADP(c);                // issue pair c loads (consumed at c+1)
        TLOOP(bx0, bx1, b0, b1, c);
        __syncthreads();
    }
    for (int c = 5; c < 16; ++c) {
        STAGE((c + 1) & 15, (c + 1) & 1);    // c=15 stages chunk 0 for loop B
        TLOOP(bx0, bx1, b0, b1, c);
        __syncthreads();
    }
    // ---- loop B: SB1 e-loop over re-staged chunks ----
    for (int c = 0; c < 16; ++c) {
        if (c < 15) STAGE(c + 1, (c + 1) & 1);
        TLOOP(bx2, bx3, b2, b3, c);
        if (c < 15) __syncthreads();
    }

    // combine the 4 g-lane copies (each saw a disjoint quarter of the e's)
    b0 = fminf(b0, __shfl_xor(b0, 16));
    b0 = fminf(b0, __shfl_xor(b0, 32));
    b1 = fminf(b1, __shfl_xor(b1, 16));
    b1 = fminf(b1, __shfl_xor(b1, 32));
    b2 = fminf(b2, __shfl_xor(b2, 16));
    b2 = fminf(b2, __shfl_xor(b2, 32));
    b3 = fminf(b3, __shfl_xor(b3, 16));
    b3 = fminf(b3, __shfl_xor(b3, 32));

    float contrib = x2s + ((g == 0) ? ((b0 + b1) + (b2 + b3)) : 0.f);
#pragma unroll
    for (int o = 32; o; o >>= 1) contrib += __shfl_down(contrib, o);

    float* wsf = reinterpret_cast<float*>(smem);   // buf0 dead since B:c=14 barrier
    if (ln == 0) wsf[wv] = contrib;
    __syncthreads();
    if (tid == 0) psc[blockIdx.x] = (wsf[0] + wsf[1]) + (wsf[2] + wsf[3]);
#undef STAGE
#undef LOADP
#undef CVT8
#undef STOREP
#undef TLOOP
}

// ---------------------------------------------------------------------------
// Kernel 2: deterministic tree-reduce of partials -> loss scalar.
// ---------------------------------------------------------------------------
__global__ __launch_bounds__(256) void finalize(const float* __restrict__ psc,
                                                float* __restrict__ out_loss) {
    __shared__ float red[256];
    const int t = threadIdx.x;
    float s = 0.f;
#pragma unroll
    for (int i = 0; i < MAIN_BLOCKS / 256; ++i) s += psc[t + i * 256];
    red[t] = s;
    __syncthreads();
    for (int h = 128; h; h >>= 1) {
        if (t < h) red[t] += red[t + h];
        __syncthreads();
    }
    if (t == 0) *out_loss = 1.25f * red[0] / (float)TOT_ELEMS;
}

extern "C" void kernel_launch(void* const* d_in, const int* in_sizes, int n_in,
                              void* d_out, int out_size, void* d_ws, size_t ws_size,
                              hipStream_t stream) {
    const float* x = (const float*)d_in[0];
    const float* emb = (const float*)d_in[1];
    float* out = (float*)d_out;
    char* ws = (char*)d_ws;

    char*  embq = ws + WS_EMBQ_OFF;
    float* e2   = (float*)(ws + WS_E2_OFF);
    float* psc  = (float*)(ws + WS_PSC_OFF);

    prep_emb<<<N_EMB, 64, 0, stream>>>(emb, embq, e2);
    vq_main<<<MAIN_BLOCKS, 256, 0, stream>>>(x, out, embq, e2, psc);
    finalize<<<1, 256, 0, stream>>>(psc, out + TOT_ELEMS);
}

// Round 12
// 110.053 us; speedup vs baseline: 1.0256x; 1.0256x over previous
//
#include <hip/hip_runtime.h>

#define EMB_DIM 256
#define HW 4096
#define N_EMB 1024
#define TOT_ELEMS (32 * HW * EMB_DIM)   // 33554432

typedef __attribute__((ext_vector_type(4))) float f32x4;
typedef unsigned long long u64;

// ws layout (bytes)
#define WS_EMBQ_OFF 0             // 256 KB fp8(e4m3) swizzled emb, 32 chunks x 8KB
#define WS_E2_OFF   262144        // 1024 f32 ||e||^2 (fp32-exact)
#define WS_PSC_OFF  266240        // 2048 f32 block partials

#define MAIN_BLOCKS 2048          // 64 rows/block, 2 waves x 32 rows
#define ESCALE 65536.0f           // emb pre-scale: |e|<2^-10 -> |ê|<64 (normal e4m3)
#define INV2SCALE 3.0517578125e-5f // 2/65536, exact fp32

typedef const __attribute__((address_space(1))) unsigned int* gas_u32p;
typedef __attribute__((address_space(3))) unsigned int* las_u32p;
__device__ __forceinline__ void gll16(const void* g, void* l) {
    __builtin_amdgcn_global_load_lds((gas_u32p)g, (las_u32p)l, 16, 0, 0);
}

// ---------------------------------------------------------------------------
// Kernel 0: emb fp32 -> fp8 e4m3 (x65536), swizzled 8KB-chunk layout + e2.
// chunk = e>>5 (32 e per 8KB chunk), row el = e&31 (256B rows),
// byte cb stored at cb ^ ((el&15)<<3)  — same XOR family as R8 (verified:
// correct numerics + 0 LDS bank conflicts; reader swz = u<<3 with el=t*16+u).
// ---------------------------------------------------------------------------
__global__ __launch_bounds__(64) void prep_emb(const float* __restrict__ emb,
                                               char* __restrict__ embq,
                                               float* __restrict__ e2) {
    const int e = blockIdx.x, ln = threadIdx.x;
    const float4 v = reinterpret_cast<const float4*>(emb)[e * 64 + ln];
    float s = v.x * v.x + v.y * v.y + v.z * v.z + v.w * v.w;

    unsigned d = 0;
    d = (unsigned)__builtin_amdgcn_cvt_pk_fp8_f32(v.x * ESCALE, v.y * ESCALE, (int)d, false);
    d = (unsigned)__builtin_amdgcn_cvt_pk_fp8_f32(v.z * ESCALE, v.w * ESCALE, (int)d, true);

    const int el = e & 31, ch = e >> 5;
    const int cb = (ln * 4) ^ ((el & 15) << 3);
    *reinterpret_cast<unsigned*>(embq + ch * 8192 + el * 256 + cb) = d;

#pragma unroll
    for (int o = 32; o; o >>= 1) s += __shfl_down(s, o);
    if (ln == 0) e2[e] = s;
}

// ---------------------------------------------------------------------------
// Kernel 1: fused copy + sum(x^2) + fp8 GEMM + min-reduction.
// R12 = R8's exact wave-level code (32 rows/wave, fragments in 32 pinned
// AGPRs, fenced prologue, same swizzle/TLOOP) at FINER BLOCK GRANULARITY:
// 2-wave blocks (64 rows), 8KB emb chunks (32 of them), 16KB LDS/block.
// 2048 blocks = 8 rounds/CU, ~6 blocks resident (reg-limited 3 waves/SIMD):
// incoming blocks' IO prologues overlap resident blocks' e-loops, breaking
// R8's launch-synchronized IO-phase/compute-phase lockstep (R9/R10/R11
// showed in-thread overlap costs occupancy and loses; R5/R9: caps spill).
// MFMA 16x16x32 fp8_fp8: D[e][m]: m=lane&15, e=4*(lane>>4)+reg.
// score = e2 - 2^-15 * (A.B)
// ---------------------------------------------------------------------------
__global__ __launch_bounds__(128)
void vq_main(const float* __restrict__ x,
             float* __restrict__ out,
             const char* __restrict__ embq,
             const float* __restrict__ e2,
             float* __restrict__ psc) {
    __shared__ char smem[16384];           // 2 x 8KB emb chunk buffers
    const int tid = threadIdx.x;
    const int wv = tid >> 6, ln = tid & 63;
    const int u = ln & 15, g = ln >> 4;    // m-lane, k-octet group

    const int row_base = blockIdx.x << 6;  // 64 rows/block
    const int b = row_base >> 12, n_base = row_base & 4095;
    const unsigned base0 = (unsigned)(b * (EMB_DIM * HW) + n_base + wv * 32 + u);

#define STAGE(CC, BUF) do {                                                   \
        const char* gs_ = embq + (CC) * 8192 + wv * 4096 + ln * 16;           \
        char* lb_ = smem + (BUF) * 8192 + wv * 4096;                          \
        _Pragma("unroll")                                                     \
        for (int i_ = 0; i_ < 4; ++i_) gll16(gs_ + i_ * 1024, lb_ + i_ * 1024); \
    } while (0)

    // ---- stage emb chunk 0 (overlaps the x prologue) ----
    STAGE(0, 0);

    // ---- load x once: copy to out, accumulate x^2, build fp8 B-fragments.
    //      Fenced per kf (16 loads in flight) — R8-verified register demand. ----
    float x2s = 0.f;
    long long bx0[8], bx1[8];

#define LDJ(KF, JP, WREG, ZREG, HI) do {                                       \
    const unsigned o_ = base0 + (unsigned)((((KF) * 32 + g * 8 + 2 * (JP))) * HW); \
    const float fa0_ = x[o_],      fb0_ = x[o_ + 16];                          \
    const float fa1_ = x[o_ + HW], fb1_ = x[o_ + HW + 16];                     \
    out[o_] = fa0_;       out[o_ + 16] = fb0_;                                 \
    out[o_ + HW] = fa1_;  out[o_ + HW + 16] = fb1_;                            \
    x2s += fa0_ * fa0_ + fb0_ * fb0_ + fa1_ * fa1_ + fb1_ * fb1_;              \
    WREG = (unsigned)__builtin_amdgcn_cvt_pk_fp8_f32(fa0_, fa1_, (int)WREG, HI); \
    ZREG = (unsigned)__builtin_amdgcn_cvt_pk_fp8_f32(fb0_, fb1_, (int)ZREG, HI); \
} while (0)

#pragma unroll
    for (int kf = 0; kf < 8; ++kf) {
        unsigned w0 = 0, w1 = 0, z0 = 0, z1 = 0;
        LDJ(kf, 0, w0, z0, false);
        LDJ(kf, 1, w0, z0, true);
        LDJ(kf, 2, w1, z1, false);
        LDJ(kf, 3, w1, z1, true);
        bx0[kf] = (long long)(((u64)w1 << 32) | w0);
        bx1[kf] = (long long)(((u64)z1 << 32) | z0);
        // pin persistent fragments into AGPRs (R4/R6/R8-verified: kills spills)
        asm volatile("" : "+a"(bx0[kf]), "+a"(bx1[kf]));
        __builtin_amdgcn_sched_barrier(0);   // no load hoisting across groups
    }
#undef LDJ

    __syncthreads();   // chunk 0 staged (barrier drains vmcnt)

    float b0 = 3.0e38f, b1 = 3.0e38f;
    const int swz = u << 3;                // (el&15)<<3 with el=t*16+u

    for (int c = 0; c < 32; ++c) {
        if (c < 31) STAGE(c + 1, (c + 1) & 1);   // next 8KB chunk, other buffer
        const char* bufb = smem + (c & 1) * 8192;
#pragma unroll
        for (int t = 0; t < 2; ++t) {
            const int rowb = (t * 16 + u) * 256;
            f32x4 a0 = {0.f, 0.f, 0.f, 0.f}, a1 = a0;
#pragma unroll
            for (int kf = 0; kf < 8; ++kf) {
                const int off = rowb + ((kf * 32 + g * 8) ^ swz);
                const long long av = *reinterpret_cast<const long long*>(bufb + off);
                a0 = __builtin_amdgcn_mfma_f32_16x16x32_fp8_fp8(av, bx0[kf], a0, 0, 0, 0);
                a1 = __builtin_amdgcn_mfma_f32_16x16x32_fp8_fp8(av, bx1[kf], a1, 0, 0, 0);
            }
            const f32x4 ev = *reinterpret_cast<const f32x4*>(e2 + c * 32 + t * 16 + g * 4);
#pragma unroll
            for (int r = 0; r < 4; ++r) {
                b0 = fminf(b0, fmaf(-INV2SCALE, a0[r], ev[r]));
                b1 = fminf(b1, fmaf(-INV2SCALE, a1[r], ev[r]));
            }
        }
        __syncthreads();   // all waves done with bufb; gll(c+1) drained
    }

    // combine the 4 g-lane copies (each saw a disjoint quarter of the e's)
    b0 = fminf(b0, __shfl_xor(b0, 16));
    b0 = fminf(b0, __shfl_xor(b0, 32));
    b1 = fminf(b1, __shfl_xor(b1, 16));
    b1 = fminf(b1, __shfl_xor(b1, 32));

    float contrib = x2s + ((g == 0) ? (b0 + b1) : 0.f);
#pragma unroll
    for (int o = 32; o; o >>= 1) contrib += __shfl_down(contrib, o);

    float* wsf = reinterpret_cast<float*>(smem);   // buf0 dead after last barrier
    if (ln == 0) wsf[wv] = contrib;
    __syncthreads();
    if (tid == 0) psc[blockIdx.x] = wsf[0] + wsf[1];
#undef STAGE
}

// ---------------------------------------------------------------------------
// Kernel 2: deterministic tree-reduce of partials -> loss scalar.
// ---------------------------------------------------------------------------
__global__ __launch_bounds__(256) void finalize(const float* __restrict__ psc,
                                                float* __restrict__ out_loss) {
    __shared__ float red[256];
    const int t = threadIdx.x;
    float s = 0.f;
#pragma unroll
    for (int i = 0; i < MAIN_BLOCKS / 256; ++i) s += psc[t + i * 256];
    red[t] = s;
    __syncthreads();
    for (int h = 128; h; h >>= 1) {
        if (t < h) red[t] += red[t + h];
        __syncthreads();
    }
    if (t == 0) *out_loss = 1.25f * red[0] / (float)TOT_ELEMS;
}

extern "C" void kernel_launch(void* const* d_in, const int* in_sizes, int n_in,
                              void* d_out, int out_size, void* d_ws, size_t ws_size,
                              hipStream_t stream) {
    const float* x = (const float*)d_in[0];
    const float* emb = (const float*)d_in[1];
    float* out = (float*)d_out;
    char* ws = (char*)d_ws;

    char*  embq = ws + WS_EMBQ_OFF;
    float* e2   = (float*)(ws + WS_E2_OFF);
    float* psc  = (float*)(ws + WS_PSC_OFF);

    prep_emb<<<N_EMB, 64, 0, stream>>>(emb, embq, e2);
    vq_main<<<MAIN_BLOCKS, 128, 0, stream>>>(x, out, embq, e2, psc);
    finalize<<<1, 256, 0, stream>>>(psc, out + TOT_ELEMS);
}

// Round 13
// 88.751 us; speedup vs baseline: 1.2718x; 1.2400x over previous
//
#include <hip/hip_runtime.h>

#define EMB_DIM 256
#define HW 4096
#define N_EMB 1024
#define TOT_ELEMS (32 * HW * EMB_DIM)   // 33554432

typedef __attribute__((ext_vector_type(4)))  float f32x4;
typedef __attribute__((ext_vector_type(16))) float f32x16;
typedef __attribute__((ext_vector_type(4)))  int   i32x4;
typedef __attribute__((ext_vector_type(8)))  int   i32x8;

// ws layout (bytes)
#define WS_EMBQ_OFF 0             // 256 KB fp8(e4m3) swizzled emb, 16 chunks x 16KB
#define WS_E2_OFF   262144        // 1024 f32 ||e||^2 (fp32-exact)
#define WS_PSC_OFF  266240        // 1024 f32 block partials

#define MAIN_BLOCKS 1024          // 128 rows/block, 4 waves x 32 rows
#define ESCALE 65536.0f           // emb pre-scale: |e|<2^-10 -> |ê|<64 (normal e4m3)
#define INV2SCALE 3.0517578125e-5f // 2/65536, exact fp32
#define SCL_ONE 127               // e8m0 exponent bias: 2^0 (neutral MX scale)

typedef const __attribute__((address_space(1))) unsigned int* gas_u32p;
typedef __attribute__((address_space(3))) unsigned int* las_u32p;
__device__ __forceinline__ void gll16(const void* g, void* l) {
    __builtin_amdgcn_global_load_lds((gas_u32p)g, (las_u32p)l, 16, 0, 0);
}

// ---------------------------------------------------------------------------
// Kernel 0: emb fp32 -> fp8 e4m3 (x65536), swizzled chunk layout + e2=||e||^2.
// chunk = e>>6 (64 e per 16KB chunk), row el = e&63 (256B rows),
// byte cb stored at cb ^ ((el&15)<<4)  — 16B-granular XOR for the reader's
// ds_read_b128 pairs (same both-sides-involution family as R8, which
// measured 0 conflicts; granularity rescaled 8 -> 16B for the 32B/lane
// f8f6f4 A-fragments).
// ---------------------------------------------------------------------------
__global__ __launch_bounds__(64) void prep_emb(const float* __restrict__ emb,
                                               char* __restrict__ embq,
                                               float* __restrict__ e2) {
    const int e = blockIdx.x, ln = threadIdx.x;
    const float4 v = reinterpret_cast<const float4*>(emb)[e * 64 + ln];
    float s = v.x * v.x + v.y * v.y + v.z * v.z + v.w * v.w;

    unsigned d = 0;
    d = (unsigned)__builtin_amdgcn_cvt_pk_fp8_f32(v.x * ESCALE, v.y * ESCALE, (int)d, false);
    d = (unsigned)__builtin_amdgcn_cvt_pk_fp8_f32(v.z * ESCALE, v.w * ESCALE, (int)d, true);

    const int el = e & 63, ch = e >> 6;
    const int cb = (ln * 4) ^ ((el & 15) << 4);
    *reinterpret_cast<unsigned*>(embq + ch * 16384 + el * 256 + cb) = d;

#pragma unroll
    for (int o = 32; o; o >>= 1) s += __shfl_down(s, o);
    if (ln == 0) e2[e] = s;
}

// ---------------------------------------------------------------------------
// Kernel 1: fused copy + sum(x^2) + MX-fp8 GEMM + min-reduction.
// R13 = R8's structure (32 rows/wave, 32 pinned AGPR B-frags, 16KB emb
// chunks dbuf'd via gll16, 1 barrier/chunk) with the MFMA upgraded to
// mfma_scale_f32_32x32x64_f8f6f4 (2.1x rate, neutral scales = 127):
// per chunk/wave: 16 ds_read_b128 + 8 MFMA (was 32 ds_read_b64 + 64 MFMA).
// Compute phase per CU drops ~33 -> ~20us (now LDS-bound).
// Layouts (m74/m101/m121-128): A/B lane = 32 consec. k-bytes, k-half=l>>5;
// D: m=lane&31, e=(reg&3)+8*(reg>>2)+4*(lane>>5).
// score = e2 - 2^-15 * (A.B)
// ---------------------------------------------------------------------------
__global__ __launch_bounds__(256)
void vq_main(const float* __restrict__ x,
             float* __restrict__ out,
             const char* __restrict__ embq,
             const float* __restrict__ e2,
             float* __restrict__ psc) {
    __shared__ char smem[32768];           // 2 x 16KB emb chunk buffers
    const int tid = threadIdx.x;
    const int wv = tid >> 6, ln = tid & 63;
    const int m = ln & 31, h = ln >> 5;    // x-row lane, k-half

    const int row_base = blockIdx.x << 7;  // 128 rows/block
    const int b = row_base >> 12, n_base = row_base & 4095;
    const unsigned base0 = (unsigned)(b * (EMB_DIM * HW) + n_base + wv * 32 + m);

#define STAGE(CC, BUF) do {                                                   \
        const char* gs_ = embq + (CC) * 16384 + wv * 4096 + ln * 16;          \
        char* lb_ = smem + (BUF) * 16384 + wv * 4096;                         \
        _Pragma("unroll")                                                     \
        for (int i_ = 0; i_ < 4; ++i_) gll16(gs_ + i_ * 1024, lb_ + i_ * 1024); \
    } while (0)

    // ---- stage emb chunk 0 (overlaps the x prologue) ----
    STAGE(0, 0);

    // ---- load x once: copy to out, accumulate x^2, build fp8 B-fragments.
    //      Lane covers row m, k = kf*64 + 32h + 0..31 (B layout). Fenced per
    //      16-load half to cap register demand (R8-verified approach). ----
    float x2s = 0.f;
    i32x8 bx[4];
#pragma unroll
    for (int kf = 0; kf < 4; ++kf) {
        const unsigned kb = base0 + (unsigned)((kf * 64 + h * 32) * HW);
        unsigned dw[8];
#pragma unroll
        for (int half = 0; half < 2; ++half) {
            float v[16];
#pragma unroll
            for (int j = 0; j < 16; ++j) {
                const unsigned o = kb + (unsigned)((half * 16 + j) * HW);
                const float f = x[o];
                out[o] = f;
                x2s += f * f;
                v[j] = f;
            }
#pragma unroll
            for (int d = 0; d < 4; ++d) {
                unsigned t = 0;
                t = (unsigned)__builtin_amdgcn_cvt_pk_fp8_f32(v[4*d],   v[4*d+1], (int)t, false);
                t = (unsigned)__builtin_amdgcn_cvt_pk_fp8_f32(v[4*d+2], v[4*d+3], (int)t, true);
                dw[half * 4 + d] = t;
            }
            __builtin_amdgcn_sched_barrier(0);   // <=16 loads in flight
        }
        i32x8 f8;
#pragma unroll
        for (int d = 0; d < 8; ++d) f8[d] = (int)dw[d];
        bx[kf] = f8;
        // pin persistent fragments into AGPRs (R4/R6/R8-verified: kills spills)
        asm volatile("" : "+a"(bx[kf]));
        __builtin_amdgcn_sched_barrier(0);       // no load hoisting across groups
    }

    __syncthreads();   // chunk 0 staged (barrier drains vmcnt)

    float best = 3.0e38f;
    const int sw = (m & 15) << 4;          // reader XOR (row&15 == m&15 both tiles)

#define SCORES(ACC, TOFF) do {                                                \
        _Pragma("unroll")                                                     \
        for (int q = 0; q < 4; ++q) {                                         \
            const f32x4 ev = *reinterpret_cast<const f32x4*>(                 \
                e2 + c * 64 + (TOFF) + q * 8 + h * 4);                        \
            _Pragma("unroll")                                                 \
            for (int r = 0; r < 4; ++r)                                       \
                best = fminf(best, fmaf(-INV2SCALE, (ACC)[q * 4 + r], ev[r])); \
        }                                                                     \
    } while (0)

    for (int c = 0; c < 16; ++c) {
        if (c < 15) STAGE(c + 1, (c + 1) & 1);   // next chunk, other buffer
        const char* bufb = smem + (c & 1) * 16384;
        const char* p0 = bufb + m * 256;         // tile0 row = m
        const char* p1 = p0 + 32 * 256;          // tile1 row = 32 + m
        f32x16 acc0 = {0.f,0.f,0.f,0.f,0.f,0.f,0.f,0.f,0.f,0.f,0.f,0.f,0.f,0.f,0.f,0.f};
        f32x16 acc1 = acc0;
#pragma unroll
        for (int kf = 0; kf < 4; ++kf) {
            const int bo = kf * 64 + h * 32;     // lane's 32 k-bytes
            const i32x4 lo0 = *reinterpret_cast<const i32x4*>(p0 + ((bo)      ^ sw));
            const i32x4 hi0 = *reinterpret_cast<const i32x4*>(p0 + ((bo + 16) ^ sw));
            const i32x4 lo1 = *reinterpret_cast<const i32x4*>(p1 + ((bo)      ^ sw));
            const i32x4 hi1 = *reinterpret_cast<const i32x4*>(p1 + ((bo + 16) ^ sw));
            i32x8 a0, a1;
#pragma unroll
            for (int d = 0; d < 4; ++d) {
                a0[d] = lo0[d]; a0[d + 4] = hi0[d];
                a1[d] = lo1[d]; a1[d + 4] = hi1[d];
            }
            acc0 = __builtin_amdgcn_mfma_scale_f32_32x32x64_f8f6f4(
                       a0, bx[kf], acc0, 0, 0, 0, SCL_ONE, 0, SCL_ONE);
            acc1 = __builtin_amdgcn_mfma_scale_f32_32x32x64_f8f6f4(
                       a1, bx[kf], acc1, 0, 0, 0, SCL_ONE, 0, SCL_ONE);
        }
        SCORES(acc0, 0);
        SCORES(acc1, 32);
        __syncthreads();   // all waves done with bufb; gll(c+1) drained
    }

    // lanes l / l+32 hold disjoint halves of the e-space for the same row m
    best = fminf(best, __shfl_xor(best, 32));

    float contrib = x2s + ((h == 0) ? best : 0.f);
#pragma unroll
    for (int o = 32; o; o >>= 1) contrib += __shfl_down(contrib, o);

    float* wsf = reinterpret_cast<float*>(smem);   // buf0 dead after last barrier
    if (ln == 0) wsf[wv] = contrib;
    __syncthreads();
    if (tid == 0) psc[blockIdx.x] = (wsf[0] + wsf[1]) + (wsf[2] + wsf[3]);
#undef STAGE
#undef SCORES
}

// ---------------------------------------------------------------------------
// Kernel 2: deterministic tree-reduce of partials -> loss scalar.
// ---------------------------------------------------------------------------
__global__ __launch_bounds__(256) void finalize(const float* __restrict__ psc,
                                                float* __restrict__ out_loss) {
    __shared__ float red[256];
    const int t = threadIdx.x;
    float s = 0.f;
#pragma unroll
    for (int i = 0; i < MAIN_BLOCKS / 256; ++i) s += psc[t + i * 256];
    red[t] = s;
    __syncthreads();
    for (int h = 128; h; h >>= 1) {
        if (t < h) red[t] += red[t + h];
        __syncthreads();
    }
    if (t == 0) *out_loss = 1.25f * red[0] / (float)TOT_ELEMS;
}

extern "C" void kernel_launch(void* const* d_in, const int* in_sizes, int n_in,
                              void* d_out, int out_size, void* d_ws, size_t ws_size,
                              hipStream_t stream) {
    const float* x = (const float*)d_in[0];
    const float* emb = (const float*)d_in[1];
    float* out = (float*)d_out;
    char* ws = (char*)d_ws;

    char*  embq = ws + WS_EMBQ_OFF;
    float* e2   = (float*)(ws + WS_E2_OFF);
    float* psc  = (float*)(ws + WS_PSC_OFF);

    prep_emb<<<N_EMB, 64, 0, stream>>>(emb, embq, e2);
    vq_main<<<MAIN_BLOCKS, 256, 0, stream>>>(x, out, embq, e2, psc);
    finalize<<<1, 256, 0, stream>>>(psc, out + TOT_ELEMS);
}